// Round 4
// baseline (181.904 us; speedup 1.0000x reference)
//
#include <hip/hip_runtime.h>
#include <hip/hip_bf16.h>

// Relative (Transformer-XL) multi-head attention, MI355X gfx950.
// B=8, T=1024, H=8, d=64, D_MODEL=512, W=2047. Output f32.
//
// Round 4:
//  - attn: T14 async-stage split (prefetch next K/V/window tile into regs
//    before compute; ds_write after post-compute barrier) -> load latency
//    hidden under MFMA/softmax/PV
//  - attn: probs moved to wave-private pr_s region (XOR-swizzled) -> B3
//    barrier removed; 2 barriers/iter
//  - attn: bijective XCD block swizzle (1024 = 8*128) -> each (b,h)'s K/V/P
//    served from one XCD's L2
//  - GEMMs: same 2-phase register prefetch (loads for kt+1 during kt MFMAs)

typedef __attribute__((ext_vector_type(8))) short short8;
typedef __attribute__((ext_vector_type(4))) float float4v;

__device__ __forceinline__ unsigned short f2bf(float f) {
  union { float f; unsigned u; } x; x.f = f;
  unsigned r = x.u + 0x7FFFu + ((x.u >> 16) & 1u);
  return (unsigned short)(r >> 16);
}
__device__ __forceinline__ float bf2f(unsigned short b) {
  union { unsigned u; float f; } x; x.u = ((unsigned)b) << 16;
  return x.f;
}

// ---------- conversion kernels ----------
__global__ void cvt_bf16_kernel(const float* __restrict__ in,
                                unsigned short* __restrict__ out, int n4) {
  int i = blockIdx.x * blockDim.x + threadIdx.x;
  if (i < n4) {
    float4 f = ((const float4*)in)[i];
    ushort4 r;
    r.x = f2bf(f.x); r.y = f2bf(f.y); r.z = f2bf(f.z); r.w = f2bf(f.w);
    ((ushort4*)out)[i] = r;
  }
}

// 5x 512x512 transposes in one launch
__global__ void transpose_cvt5_kernel(const float* __restrict__ Wq,
                                      const float* __restrict__ Wk,
                                      const float* __restrict__ Wv,
                                      const float* __restrict__ Wp,
                                      const float* __restrict__ Wo,
                                      unsigned short* __restrict__ dst) {
  int y = blockIdx.y;
  const float* w = (y == 0) ? Wq : (y == 1) ? Wk : (y == 2) ? Wv : (y == 3) ? Wp : Wo;
  unsigned short* wt = dst + (size_t)y * 262144;
  int idx = blockIdx.x * 256 + threadIdx.x;
  int kk = idx >> 9, n = idx & 511;
  wt[(n << 9) | kk] = f2bf(w[idx]);
}

// ---------- merged QKV projection GEMM ----------
__global__ __launch_bounds__(256) void qkv_gemm_kernel(
    const unsigned short* __restrict__ A,
    const unsigned short* __restrict__ Bt,
    const float* __restrict__ bq,
    const float* __restrict__ uvec,
    const float* __restrict__ vvec,
    unsigned short* __restrict__ QU, unsigned short* __restrict__ QV,
    unsigned short* __restrict__ Kb, unsigned short* __restrict__ Vt) {
  __shared__ __align__(16) unsigned short As[64][72];
  __shared__ __align__(16) unsigned short Bs[64][72];
  int mt = blockIdx.x, nt = blockIdx.y;
  int tid = threadIdx.x;
  int lr = tid >> 2, lc = (tid & 3) << 4;
  int lane = tid & 63, wave = tid >> 6;
  int l15 = lane & 15, g = lane >> 4;

  const unsigned short* Ap = A + (size_t)(mt * 64 + lr) * 512 + lc;
  const unsigned short* Bp = Bt + (size_t)(nt * 64 + lr) * 512 + lc;

  uint4 a0 = *(const uint4*)Ap, a1 = *(const uint4*)(Ap + 8);
  uint4 b0 = *(const uint4*)Bp, b1 = *(const uint4*)(Bp + 8);
  float4v acc[4] = {};
  for (int kt = 0; kt < 8; ++kt) {
    *(uint4*)&As[lr][lc]     = a0;
    *(uint4*)&As[lr][lc + 8] = a1;
    *(uint4*)&Bs[lr][lc]     = b0;
    *(uint4*)&Bs[lr][lc + 8] = b1;
    __syncthreads();
    if (kt < 7) {
      a0 = *(const uint4*)(Ap + (kt + 1) * 64);
      a1 = *(const uint4*)(Ap + (kt + 1) * 64 + 8);
      b0 = *(const uint4*)(Bp + (kt + 1) * 64);
      b1 = *(const uint4*)(Bp + (kt + 1) * 64 + 8);
    }
#pragma unroll
    for (int ks = 0; ks < 2; ++ks) {
      short8 a = *(const short8*)&As[wave * 16 + l15][ks * 32 + g * 8];
#pragma unroll
      for (int fn = 0; fn < 4; ++fn) {
        short8 b = *(const short8*)&Bs[fn * 16 + l15][ks * 32 + g * 8];
        acc[fn] = __builtin_amdgcn_mfma_f32_16x16x32_bf16(a, b, acc[fn], 0, 0, 0);
      }
    }
    if (kt < 7) __syncthreads();
  }
  int rl = wave * 16 + ((lane >> 4) << 2);
  if (nt < 8) {
#pragma unroll
    for (int fn = 0; fn < 4; ++fn) {
      int col = nt * 64 + fn * 16 + l15;
      float bs = bq[col], uu = uvec[col], vv = vvec[col];
#pragma unroll
      for (int r = 0; r < 4; ++r) {
        size_t idx = (size_t)(mt * 64 + rl + r) * 512 + col;
        float base = acc[fn][r] + bs;
        QU[idx] = f2bf(base + uu);
        QV[idx] = f2bf(base + vv);
      }
    }
  } else if (nt < 16) {
#pragma unroll
    for (int fn = 0; fn < 4; ++fn) {
      int col = (nt - 8) * 64 + fn * 16 + l15;
#pragma unroll
      for (int r = 0; r < 4; ++r)
        Kb[(size_t)(mt * 64 + rl + r) * 512 + col] = f2bf(acc[fn][r]);
    }
  } else {
    __syncthreads();
#pragma unroll
    for (int fn = 0; fn < 4; ++fn)
#pragma unroll
      for (int r = 0; r < 4; ++r)
        As[rl + r][fn * 16 + l15] = f2bf(acc[fn][r]);
    __syncthreads();
    int d = tid >> 2, sc = (tid & 3) * 16;
    int bb = mt >> 4, s0 = (mt & 15) * 64, h = nt - 16;
    unsigned short tmp[16];
#pragma unroll
    for (int j = 0; j < 16; ++j) tmp[j] = As[sc + j][d];
    unsigned short* op = Vt + ((size_t)((bb * 8 + h) * 64 + d)) * 1024 + s0 + sc;
    *(uint4*)op       = *(uint4*)tmp;
    *(uint4*)(op + 8) = *(uint4*)(tmp + 8);
  }
}

// ---------- generic bf16 MFMA GEMM (pos projection, out projection) ----------
__global__ __launch_bounds__(256) void gemm_kernel(
    const unsigned short* __restrict__ A,
    const unsigned short* __restrict__ Bt,
    const float* __restrict__ bias,
    unsigned short* __restrict__ Cb,
    float* __restrict__ Cf,
    int M, int f32out) {
  __shared__ __align__(16) unsigned short As[64][72];
  __shared__ __align__(16) unsigned short Bs[64][72];
  int mt = blockIdx.x, nt = blockIdx.y;
  int tid = threadIdx.x;
  int lr = tid >> 2, lc = (tid & 3) << 4;
  int lane = tid & 63, wave = tid >> 6;

  int arow = mt * 64 + lr; if (arow >= M) arow = M - 1;
  const unsigned short* Ap = A + (size_t)arow * 512 + lc;
  const unsigned short* Bp = Bt + (size_t)(nt * 64 + lr) * 512 + lc;

  uint4 a0 = *(const uint4*)Ap, a1 = *(const uint4*)(Ap + 8);
  uint4 b0 = *(const uint4*)Bp, b1 = *(const uint4*)(Bp + 8);
  float4v acc[4] = {};
  for (int kt = 0; kt < 8; ++kt) {
    *(uint4*)&As[lr][lc]     = a0;
    *(uint4*)&As[lr][lc + 8] = a1;
    *(uint4*)&Bs[lr][lc]     = b0;
    *(uint4*)&Bs[lr][lc + 8] = b1;
    __syncthreads();
    if (kt < 7) {
      a0 = *(const uint4*)(Ap + (kt + 1) * 64);
      a1 = *(const uint4*)(Ap + (kt + 1) * 64 + 8);
      b0 = *(const uint4*)(Bp + (kt + 1) * 64);
      b1 = *(const uint4*)(Bp + (kt + 1) * 64 + 8);
    }
#pragma unroll
    for (int ks = 0; ks < 2; ++ks) {
      short8 a = *(const short8*)&As[wave * 16 + (lane & 15)][ks * 32 + (lane >> 4) * 8];
#pragma unroll
      for (int fn = 0; fn < 4; ++fn) {
        short8 b = *(const short8*)&Bs[fn * 16 + (lane & 15)][ks * 32 + (lane >> 4) * 8];
        acc[fn] = __builtin_amdgcn_mfma_f32_16x16x32_bf16(a, b, acc[fn], 0, 0, 0);
      }
    }
    if (kt < 7) __syncthreads();
  }
  int rbase = mt * 64 + wave * 16 + ((lane >> 4) << 2);
  int cb = nt * 64 + (lane & 15);
#pragma unroll
  for (int fn = 0; fn < 4; ++fn) {
    int col = cb + fn * 16;
    float bs = bias ? bias[col] : 0.0f;
#pragma unroll
    for (int r = 0; r < 4; ++r) {
      int row = rbase + r;
      if (row < M) {
        float val = acc[fn][r] + bs;
        if (f32out) Cf[(size_t)row * 512 + col] = val;
        else        Cb[(size_t)row * 512 + col] = f2bf(val);
      }
    }
  }
}

// ---------- fused relative attention ----------
// 1D grid 1024 (XCD-swizzled), 256 threads (4 waves x 16 Q-rows).
#define SHIFT_C(C)                                                         \
  _Pragma("unroll")                                                        \
  for (int fn = 0; fn < 4; ++fn) {                                         \
    _Pragma("unroll")                                                      \
    for (int r = 0; r < 4; ++r) {                                          \
      int srcLane = (lane & 48) | ((l15 - 4 * g - r - 1) & 15);            \
      float v0 = __shfl(accP[fn + C][r], srcLane);                         \
      float v1 = __shfl(accP[fn + C + 1][r], srcLane);                     \
      float sh = (l15 >= 4 * g + r + 1) ? v1 : v0;                         \
      accS[fn][r] = (accS[fn][r] + sh) * 0.125f;                           \
    }                                                                      \
  }

__global__ __launch_bounds__(256, 3) void attn_kernel(
    const unsigned short* __restrict__ QU,  // (B*T,512) bf16 = q+bq+u
    const unsigned short* __restrict__ QV,  // (B*T,512) bf16 = q+bq+v
    const unsigned short* __restrict__ K,   // (B*T,512) bf16
    const unsigned short* __restrict__ Vt,  // [b][h][d][s] bf16
    const unsigned short* __restrict__ P,   // (2047,512) bf16
    unsigned short* __restrict__ O) {       // (B*T,512) bf16
  __shared__ __align__(16) unsigned short k_s[64][72];
  __shared__ __align__(16) unsigned short vt_s[64][72];
  __shared__ __align__(16) unsigned short win_s[128 * 72];
  // wave-private probs region: rows [wave*16, wave*16+16), stride 72,
  // col XOR-swizzled by ((row>>2)&3)<<4 (within wave: g<<4)
  __shared__ __align__(16) unsigned short pr_s[64 * 72];

  // XCD swizzle: 1024 blocks = 8 XCDs x 128; XCD x owns logical ids
  // [x*128, x*128+128) = complete (b,h) groups
  int pid = blockIdx.x;
  int wid = (pid & 7) * 128 + (pid >> 3);
  int tt = wid & 15, h = (wid >> 4) & 7, b = wid >> 7;
  int t0 = tt * 64;
  int tid = threadIdx.x, lane = tid & 63, wave = tid >> 6;
  int lr = tid >> 2, lc = (tid & 3) << 4;
  int l15 = lane & 15, g = lane >> 4;
  int w16 = wave * 16;
  int r2 = tid >> 1, c2 = (tid & 1) << 5;

  // Q fragments straight from global (held in regs for the whole block)
  short8 aqu[2], aqv[2];
  {
    size_t qoff = (size_t)(b * 1024 + t0 + w16 + l15) * 512 + h * 64 + g * 8;
    aqu[0] = *(const short8*)(QU + qoff);
    aqu[1] = *(const short8*)(QU + qoff + 32);
    aqv[0] = *(const short8*)(QV + qoff);
    aqv[1] = *(const short8*)(QV + qoff + 32);
  }

  const unsigned short* Kbase = K + (size_t)(b * 1024) * 512 + h * 64;
  const unsigned short* Vbase = Vt + (size_t)((b * 8 + h) * 64) * 1024;

  uint4 pk0, pk1, pv0, pv1, pw0, pw1, pw2, pw3;
#define LOADT(stn) {                                                        \
    int s0n = (stn) * 64;                                                   \
    const unsigned short* kp = Kbase + (size_t)(s0n + lr) * 512 + lc;       \
    pk0 = *(const uint4*)kp; pk1 = *(const uint4*)(kp + 8);                 \
    const unsigned short* vp = Vbase + (size_t)lr * 1024 + s0n + lc;        \
    pv0 = *(const uint4*)vp; pv1 = *(const uint4*)(vp + 8);                 \
    int wr = s0n - t0 + 960 + r2; if (wr > 2046) wr = 2046;                 \
    const unsigned short* pp = P + (size_t)wr * 512 + h * 64 + c2;          \
    pw0 = *(const uint4*)pp;        pw1 = *(const uint4*)(pp + 8);          \
    pw2 = *(const uint4*)(pp + 16); pw3 = *(const uint4*)(pp + 24); }

#define STORET {                                                            \
    *(uint4*)&k_s[lr][lc]      = pk0; *(uint4*)&k_s[lr][lc + 8]  = pk1;     \
    *(uint4*)&vt_s[lr][lc]     = pv0; *(uint4*)&vt_s[lr][lc + 8] = pv1;     \
    unsigned short* dp = &win_s[r2 * 72 + c2];                              \
    *(uint4*)dp        = pw0; *(uint4*)(dp + 8)  = pw1;                     \
    *(uint4*)(dp + 16) = pw2; *(uint4*)(dp + 24) = pw3; }

  float4v accO[4] = {};
  float m_r[4] = {-1e30f, -1e30f, -1e30f, -1e30f};
  float l_r[4] = {0.f, 0.f, 0.f, 0.f};

  LOADT(0);
  STORET;
  __syncthreads();

  for (int st = 0; st < 16; ++st) {
    // issue next tile's global loads (latency hides under compute)
    LOADT(st + 1 < 16 ? st + 1 : 15);

    // content (64x64, A=QU) and pos-window (64x128, A=QV) score MFMAs
    float4v accS[4] = {}; float4v accP[8] = {};
#pragma unroll
    for (int ks = 0; ks < 2; ++ks) {
#pragma unroll
      for (int fn = 0; fn < 4; ++fn) {
        short8 bk = *(const short8*)&k_s[fn * 16 + l15][ks * 32 + g * 8];
        accS[fn] = __builtin_amdgcn_mfma_f32_16x16x32_bf16(aqu[ks], bk, accS[fn], 0, 0, 0);
      }
#pragma unroll
      for (int fn = 0; fn < 8; ++fn) {
        short8 bp = *(const short8*)&win_s[(fn * 16 + l15) * 72 + ks * 32 + g * 8];
        accP[fn] = __builtin_amdgcn_mfma_f32_16x16x32_bf16(aqv[ks], bp, accP[fn], 0, 0, 0);
      }
    }

    // relative shift via in-register lane rotation (wave-uniform branch)
    if (wave == 0)      { SHIFT_C(3) }
    else if (wave == 1) { SHIFT_C(2) }
    else if (wave == 2) { SHIFT_C(1) }
    else                { SHIFT_C(0) }

    // online softmax (wave-local); probs -> pr_s (wave-private, swizzled)
    float alpha[4];
#pragma unroll
    for (int r = 0; r < 4; ++r) {
      float rowmax = fmaxf(fmaxf(accS[0][r], accS[1][r]),
                           fmaxf(accS[2][r], accS[3][r]));
      rowmax = fmaxf(rowmax, __shfl_xor(rowmax, 1));
      rowmax = fmaxf(rowmax, __shfl_xor(rowmax, 2));
      rowmax = fmaxf(rowmax, __shfl_xor(rowmax, 4));
      rowmax = fmaxf(rowmax, __shfl_xor(rowmax, 8));
      float mnew = fmaxf(m_r[r], rowmax);
      float al = __expf(m_r[r] - mnew);
      float rs = 0.f;
#pragma unroll
      for (int fn = 0; fn < 4; ++fn) {
        float e = __expf(accS[fn][r] - mnew);
        pr_s[(w16 + 4 * g + r) * 72 + ((fn * 16 + l15) ^ (g << 4))] = f2bf(e);
        rs += e;
      }
      rs += __shfl_xor(rs, 1); rs += __shfl_xor(rs, 2);
      rs += __shfl_xor(rs, 4); rs += __shfl_xor(rs, 8);
      l_r[r] = l_r[r] * al + rs;
      m_r[r] = mnew;
      alpha[r] = al;
    }
#pragma unroll
    for (int fn = 0; fn < 4; ++fn)
#pragma unroll
      for (int r = 0; r < 4; ++r) accO[fn][r] *= alpha[r];

    // PV: accO += P @ V  (A-frag: own probs rows, swizzle-read; B: vt_s)
#pragma unroll
    for (int ks = 0; ks < 2; ++ks) {
      short8 ap = *(const short8*)&pr_s[(w16 + l15) * 72 +
                                        ((ks * 32 + g * 8) ^ ((l15 >> 2) << 4))];
#pragma unroll
      for (int fn = 0; fn < 4; ++fn) {
        short8 bv = *(const short8*)&vt_s[fn * 16 + l15][ks * 32 + g * 8];
        accO[fn] = __builtin_amdgcn_mfma_f32_16x16x32_bf16(ap, bv, accO[fn], 0, 0, 0);
      }
    }

    if (st < 15) {
      __syncthreads();      // all waves done reading k_s/vt_s/win_s
      STORET;               // vmcnt drain happens here, after compute
      __syncthreads();      // staging visible
    }
  }

  // epilogue: O / l -> bf16
#pragma unroll
  for (int fn = 0; fn < 4; ++fn) {
    int dcol = fn * 16 + l15;
#pragma unroll
    for (int r = 0; r < 4; ++r) {
      int row = t0 + w16 + 4 * g + r;
      float o = accO[fn][r] / l_r[r];
      O[(size_t)(b * 1024 + row) * 512 + h * 64 + dcol] = f2bf(o);
    }
  }
#undef LOADT
#undef STORET
}

// ---------- host ----------
extern "C" void kernel_launch(void* const* d_in, const int* in_sizes, int n_in,
                              void* d_out, int out_size, void* d_ws, size_t ws_size,
                              hipStream_t stream) {
  const float* x       = (const float*)d_in[0];
  const float* pos_emb = (const float*)d_in[1];
  const float* Wq      = (const float*)d_in[2];
  const float* bq      = (const float*)d_in[3];
  const float* Wk      = (const float*)d_in[4];
  const float* Wv      = (const float*)d_in[5];
  const float* Wp      = (const float*)d_in[6];
  const float* Wo      = (const float*)d_in[7];
  const float* bo      = (const float*)d_in[8];
  const float* u       = (const float*)d_in[9];
  const float* v       = (const float*)d_in[10];

  char* ws = (char*)d_ws;
  unsigned short* xb   = (unsigned short*)ws; ws += (size_t)8192 * 512 * 2;
  unsigned short* peb  = (unsigned short*)ws; ws += (size_t)2048 * 512 * 2;
  unsigned short* wqkv = (unsigned short*)ws; ws += (size_t)5 * 512 * 512 * 2;
  unsigned short* qub  = (unsigned short*)ws; ws += (size_t)8192 * 512 * 2;
  unsigned short* qvb  = (unsigned short*)ws; ws += (size_t)8192 * 512 * 2;
  unsigned short* kb   = (unsigned short*)ws; ws += (size_t)8192 * 512 * 2;
  unsigned short* vtb  = (unsigned short*)ws; ws += (size_t)8192 * 512 * 2;
  unsigned short* pb   = (unsigned short*)ws; ws += (size_t)2048 * 512 * 2;
  unsigned short* attb = (unsigned short*)ws; ws += (size_t)8192 * 512 * 2;

  cvt_bf16_kernel<<<4096, 256, 0, stream>>>(x, xb, 1048576);
  cvt_bf16_kernel<<<1024, 256, 0, stream>>>(pos_emb, peb, 262016);
  transpose_cvt5_kernel<<<dim3(1024, 5), 256, 0, stream>>>(Wq, Wk, Wv, Wp, Wo, wqkv);
  unsigned short* wpt_p = wqkv + (size_t)3 * 262144;
  unsigned short* wot_p = wqkv + (size_t)4 * 262144;

  qkv_gemm_kernel<<<dim3(128, 24), 256, 0, stream>>>(xb, wqkv, bq, u, v,
                                                     qub, qvb, kb, vtb);
  gemm_kernel<<<dim3(32, 8), 256, 0, stream>>>(peb, wpt_p, nullptr, pb, nullptr, 2047, 0);

  attn_kernel<<<1024, 256, 0, stream>>>(qub, qvb, kb, vtb, pb, attb);

  gemm_kernel<<<dim3(128, 8), 256, 0, stream>>>(attb, wot_p, bo, nullptr,
                                                (float*)d_out, 8192, 1);
}